// Round 4
// baseline (307.867 us; speedup 1.0000x reference)
//
#include <hip/hip_runtime.h>
#include <hip/hip_cooperative_groups.h>

// FTScanBasic: inclusive cumsum along axis 0 of xs[8192][4096] fp32.
// d_out layout: [0..4095] = final carry (ys[-1]), [4096..] = ys flat.
//
// Fused cooperative two-phase chunked scan (single dispatch):
//   phase A: per-chunk column sums -> partials[CHUNKS][D4] (2 MiB ws).
//            Side effect: parks all of xs (134 MB) in the 256 MiB LLC.
//   grid.sync()  -- one device-scope barrier, replaces the kernel boundary
//                   (round-1's per-block agent fences regressed 5x; this is
//                   a single collective fence, not 2048 of them).
//   phase B: sum <chunk predecessor partial rows (L2-hot, pipelined), then
//            stream the chunk: run += x (LLC-hot), nontemporal-write ys.
//            Chunk 127 writes carry.
// ys/carry stores NONTEMPORAL so 134 MB of ys writes don't evict the xs
// lines phase B re-reads (134+134 > 256 MiB LLC).
// Fallback: proven two-pass version if cooperative launch is unavailable.

constexpr int T_ROWS = 8192;
constexpr int D_COLS = 4096;
constexpr int D4 = D_COLS / 4;          // 1024 float4 per row
constexpr int CHUNKS = 128;
constexpr int RPC = T_ROWS / CHUNKS;    // 64 rows per chunk
constexpr int THREADS = 256;
constexpr int COL_BLOCKS = D4 / THREADS; // 4
constexpr int TILES = CHUNKS * COL_BLOCKS; // 512 blocks = 2/CU, co-resident

namespace cg = cooperative_groups;

typedef float f32x4 __attribute__((ext_vector_type(4)));

__device__ __forceinline__ void acc4(float4& a, const float4& v) {
    a.x += v.x; a.y += v.y; a.z += v.z; a.w += v.w;
}

__device__ __forceinline__ void nt_store4(const float4& v, float4* p) {
    f32x4 w; w.x = v.x; w.y = v.y; w.z = v.z; w.w = v.w;
    __builtin_nontemporal_store(w, reinterpret_cast<f32x4*>(p));
}

__global__ __launch_bounds__(THREADS)
void scan_coop(const float4* __restrict__ xs, float4* __restrict__ partials,
               float4* __restrict__ ys, float4* __restrict__ carry) {
    const int tile  = blockIdx.x;           // 0..511
    const int chunk = tile >> 2;            // / COL_BLOCKS
    const int cb    = tile & 3;
    const int col4  = cb * THREADS + (int)threadIdx.x;   // 0..1023
    const size_t base = (size_t)chunk * RPC * D4 + col4;

    // ---- phase A: chunk column sums ----
    float4 acc = make_float4(0.f, 0.f, 0.f, 0.f);
#pragma unroll 8
    for (int r = 0; r < RPC; ++r) {
        acc4(acc, xs[base + (size_t)r * D4]);
    }
    partials[(size_t)chunk * D4 + col4] = acc;

    cg::this_grid().sync();

    // ---- phase B: exclusive prefix, then stream the chunk ----
    float4 run = make_float4(0.f, 0.f, 0.f, 0.f);
#pragma unroll 4
    for (int c = 0; c < chunk; ++c) {
        acc4(run, partials[(size_t)c * D4 + col4]);
    }
#pragma unroll 8
    for (int r = 0; r < RPC; ++r) {
        acc4(run, xs[base + (size_t)r * D4]);
        nt_store4(run, &ys[base + (size_t)r * D4]);
    }
    if (chunk == CHUNKS - 1) {
        nt_store4(run, &carry[col4]);  // ys[-1]
    }
}

// ---------------- fallback: proven two-pass ----------------
__global__ __launch_bounds__(THREADS)
void scan_pass1(const float4* __restrict__ xs, float4* __restrict__ partials) {
    const int col4  = blockIdx.x * THREADS + threadIdx.x;
    const int chunk = blockIdx.y;
    const float4* p = xs + (size_t)chunk * RPC * D4 + col4;
    float4 acc = make_float4(0.f, 0.f, 0.f, 0.f);
#pragma unroll 8
    for (int r = 0; r < RPC; ++r) acc4(acc, p[(size_t)r * D4]);
    partials[(size_t)chunk * D4 + col4] = acc;
}

__global__ __launch_bounds__(THREADS)
void scan_pass2(const float4* __restrict__ xs, const float4* __restrict__ partials,
                float4* __restrict__ ys, float4* __restrict__ carry) {
    const int col4  = blockIdx.x * THREADS + threadIdx.x;
    const int chunk = blockIdx.y;
    float4 run = make_float4(0.f, 0.f, 0.f, 0.f);
#pragma unroll 4
    for (int c = 0; c < chunk; ++c) acc4(run, partials[(size_t)c * D4 + col4]);
    const size_t base = (size_t)chunk * RPC * D4 + col4;
#pragma unroll 8
    for (int r = 0; r < RPC; ++r) {
        acc4(run, xs[base + (size_t)r * D4]);
        nt_store4(run, &ys[base + (size_t)r * D4]);
    }
    if (chunk == CHUNKS - 1) nt_store4(run, &carry[col4]);
}

extern "C" void kernel_launch(void* const* d_in, const int* in_sizes, int n_in,
                              void* d_out, int out_size, void* d_ws, size_t ws_size,
                              hipStream_t stream) {
    const float4* xs = (const float4*)d_in[0];
    float* out = (float*)d_out;
    float4* carry = (float4*)out;                 // first 4096 floats
    float4* ys = (float4*)(out + D_COLS);         // 16 KiB offset, 16B-aligned
    float4* partials = (float4*)d_ws;             // 128 * 1024 * 16 B = 2 MiB

    void* args[] = { (void*)&xs, (void*)&partials, (void*)&ys, (void*)&carry };
    hipError_t err = hipLaunchCooperativeKernel(
        (void*)scan_coop, dim3(TILES), dim3(THREADS), args, 0, stream);

    if (err != hipSuccess) {
        dim3 grid(COL_BLOCKS, CHUNKS);            // 4 x 128 = 512 blocks
        scan_pass1<<<grid, THREADS, 0, stream>>>(xs, partials);
        scan_pass2<<<grid, THREADS, 0, stream>>>(xs, partials, ys, carry);
    }
}

// Round 5
// 247.734 us; speedup vs baseline: 1.2427x; 1.2427x over previous
//
#include <hip/hip_runtime.h>

// FTScanBasic: inclusive cumsum along axis 0 of xs[8192][4096] fp32.
// d_out layout: [0..4095] = final carry (ys[-1]), [4096..] = ys flat.
//
// Two-pass chunked scan. History:
//   r1: fused decoupled-lookback  -> 5x regression (per-block agent fences).
//   r4: cooperative grid.sync fusion -> 139us vs 77us (device-scope barrier
//       invalidates all L2s; phase B restarts cold). Kernel boundary wins.
//   r3: two-pass + nt ys stores = best (kernels ~77us of dur 245.3).
// This version: r3 + (a) NONTEMPORAL xs loads in pass2 — xs is dead after
// this read; no-allocate keeps the 2 MiB partials (reused by all chunk-
// blocks per XCD) L2-resident instead of being evicted by 134 MB of dead
// lines; (b) prefix unroll 4->8 (more independent loads in flight);
// (c) pass2 dispatches heavy-prefix chunks first (reverse blockIdx.y map).
//
//   pass1: per-chunk column sums -> partials[CHUNKS][D4] (2 MiB ws).
//          Side effect: parks all of xs (134 MB) in the 256 MiB LLC.
//   pass2: sum <chunk predecessor partial rows (L2-hot), then stream the
//          chunk: run += x (LLC-hot nt-load), nt-store inclusive row.
//          Chunk 127 writes carry. nt stores keep ys from evicting xs.

constexpr int T_ROWS = 8192;
constexpr int D_COLS = 4096;
constexpr int D4 = D_COLS / 4;          // 1024 float4 per row
constexpr int CHUNKS = 128;
constexpr int RPC = T_ROWS / CHUNKS;    // 64 rows per chunk
constexpr int THREADS = 256;
constexpr int COL_BLOCKS = D4 / THREADS; // 4

typedef float f32x4 __attribute__((ext_vector_type(4)));

__device__ __forceinline__ void acc4(float4& a, const float4& v) {
    a.x += v.x; a.y += v.y; a.z += v.z; a.w += v.w;
}

__device__ __forceinline__ void nt_store4(const float4& v, float4* p) {
    f32x4 w; w.x = v.x; w.y = v.y; w.z = v.z; w.w = v.w;
    __builtin_nontemporal_store(w, reinterpret_cast<f32x4*>(p));
}

__device__ __forceinline__ float4 nt_load4(const float4* p) {
    f32x4 w = __builtin_nontemporal_load(reinterpret_cast<const f32x4*>(p));
    return make_float4(w.x, w.y, w.z, w.w);
}

__global__ __launch_bounds__(THREADS)
void scan_pass1(const float4* __restrict__ xs, float4* __restrict__ partials) {
    const int col4  = blockIdx.x * THREADS + threadIdx.x;  // 0..1023
    const int chunk = blockIdx.y;
    const float4* p = xs + (size_t)chunk * RPC * D4 + col4;
    float4 acc = make_float4(0.f, 0.f, 0.f, 0.f);
#pragma unroll 8
    for (int r = 0; r < RPC; ++r) {
        acc4(acc, p[(size_t)r * D4]);
    }
    partials[(size_t)chunk * D4 + col4] = acc;   // cacheable: re-read in pass2
}

__global__ __launch_bounds__(THREADS)
void scan_pass2(const float4* __restrict__ xs, const float4* __restrict__ partials,
                float4* __restrict__ ys, float4* __restrict__ carry) {
    const int col4  = blockIdx.x * THREADS + threadIdx.x;
    const int chunk = CHUNKS - 1 - blockIdx.y;   // heavy prefix blocks first

    // Exclusive prefix for this chunk: sum predecessor partial rows directly.
    // <=127 independent coalesced L2-hot loads, 8 in flight.
    float4 run = make_float4(0.f, 0.f, 0.f, 0.f);
#pragma unroll 8
    for (int c = 0; c < chunk; ++c) {
        acc4(run, partials[(size_t)c * D4 + col4]);
    }

    // Stream this chunk. xs reads: LLC-hot (parked by pass1), nontemporal
    // (dead after this use -> don't evict partials / don't allocate).
    // ys writes: nontemporal (don't evict xs for the still-running blocks).
    const size_t base = (size_t)chunk * RPC * D4 + col4;
#pragma unroll 8
    for (int r = 0; r < RPC; ++r) {
        acc4(run, nt_load4(&xs[base + (size_t)r * D4]));
        nt_store4(run, &ys[base + (size_t)r * D4]);
    }

    if (chunk == CHUNKS - 1) {
        nt_store4(run, &carry[col4]);  // ys[-1]
    }
}

extern "C" void kernel_launch(void* const* d_in, const int* in_sizes, int n_in,
                              void* d_out, int out_size, void* d_ws, size_t ws_size,
                              hipStream_t stream) {
    const float4* xs = (const float4*)d_in[0];
    float* out = (float*)d_out;
    float4* carry = (float4*)out;                 // first 4096 floats
    float4* ys = (float4*)(out + D_COLS);         // 16 KiB offset, 16B-aligned
    float4* partials = (float4*)d_ws;             // 128 * 1024 * 16 B = 2 MiB

    dim3 grid(COL_BLOCKS, CHUNKS);                // 4 x 128 = 512 blocks
    scan_pass1<<<grid, THREADS, 0, stream>>>(xs, partials);
    scan_pass2<<<grid, THREADS, 0, stream>>>(xs, partials, ys, carry);
}